// Round 10
// baseline (406.379 us; speedup 1.0000x reference)
//
#include <hip/hip_runtime.h>
#include <hip/hip_bf16.h>

typedef __attribute__((ext_vector_type(4))) float f32x4;
typedef __attribute__((ext_vector_type(8))) short s16x8;
typedef unsigned short ushort_t;

#define N_DIM 4096
#define C_DIM 512

static __device__ __forceinline__ unsigned short f2bf(float f) {
    union { float f; unsigned u; } v; v.f = f;
    unsigned r = v.u + 0x7FFFu + ((v.u >> 16) & 1u);
    return (unsigned short)(r >> 16);
}
static __device__ __forceinline__ float bf2f(unsigned short u) {
    union { unsigned u; float f; } v; v.u = ((unsigned)u) << 16;
    return v.f;
}

// ---------------- GroupNorm stats
__global__ void gn_stats_kernel(const float* __restrict__ x, float* __restrict__ stats) {
    int bg = blockIdx.x;
    int b = bg >> 5, g = bg & 31;
    const float* base = x + (size_t)b * (N_DIM * C_DIM) + g * 16;
    float sum = 0.f, ss = 0.f;
    for (int n = threadIdx.x; n < N_DIM; n += 256) {
        const float4* p = (const float4*)(base + (size_t)n * C_DIM);
        #pragma unroll
        for (int t = 0; t < 4; ++t) {
            float4 v = p[t];
            sum += v.x + v.y + v.z + v.w;
            ss  += v.x*v.x + v.y*v.y + v.z*v.z + v.w*v.w;
        }
    }
    #pragma unroll
    for (int o = 32; o > 0; o >>= 1) {
        sum += __shfl_down(sum, o);
        ss  += __shfl_down(ss, o);
    }
    __shared__ float red[8];
    int wid = threadIdx.x >> 6, lane = threadIdx.x & 63;
    if (lane == 0) { red[wid*2] = sum; red[wid*2+1] = ss; }
    __syncthreads();
    if (threadIdx.x == 0) {
        sum = red[0]+red[2]+red[4]+red[6];
        ss  = red[1]+red[3]+red[5]+red[7];
        float mean = sum * (1.f/65536.f);
        float var  = ss  * (1.f/65536.f) - mean*mean;
        stats[bg*2]   = mean;
        stats[bg*2+1] = rsqrtf(var + 1e-5f);
    }
}

// ---------------- normalize + gamma/beta + cast to bf16
__global__ void gn_norm_kernel(const float* __restrict__ x, const float* __restrict__ gamma,
                               const float* __restrict__ beta, const float* __restrict__ stats,
                               ushort_t* __restrict__ xn) {
    size_t i = ((size_t)blockIdx.x * 256 + threadIdx.x) * 4;
    int c = (int)(i & 511);
    int b = (int)(i >> 21);
    int bg = b*32 + (c >> 4);
    float mean = stats[bg*2], rstd = stats[bg*2+1];
    float4 v  = *(const float4*)(x + i);
    float4 ga = *(const float4*)(gamma + c);
    float4 be = *(const float4*)(beta + c);
    ushort4 o;
    o.x = f2bf((v.x - mean) * rstd * ga.x + be.x);
    o.y = f2bf((v.y - mean) * rstd * ga.y + be.y);
    o.z = f2bf((v.z - mean) * rstd * ga.z + be.z);
    o.w = f2bf((v.w - mean) * rstd * ga.w + be.w);
    *(ushort4*)(xn + i) = o;
}

// ---------------- weights: fp32 [Cin][Cout] -> bf16 transposed [Cout][Cin], 4 mats
__global__ void wconv_kernel(const float* __restrict__ wq, const float* __restrict__ wk,
                             const float* __restrict__ wv, const float* __restrict__ wp,
                             ushort_t* __restrict__ wt) {
    int idx = blockIdx.x * 256 + threadIdx.x;
    int m = idx >> 18;
    int r = idx & 262143;
    int ci = r >> 9, co = r & 511;
    const float* w = (m == 0) ? wq : (m == 1) ? wk : (m == 2) ? wv : wp;
    wt[(size_t)m * 262144 + (size_t)co * 512 + ci] = f2bf(w[(size_t)ci * 512 + co]);
}

// ---------------- QKV GEMM, m97-style 128x128 tile (verified R9)
__global__ __launch_bounds__(256) void qkv_kernel(const ushort_t* __restrict__ xn, const ushort_t* __restrict__ wt,
                         const float* __restrict__ bq, const float* __restrict__ bk, const float* __restrict__ bv,
                         ushort_t* __restrict__ q, ushort_t* __restrict__ k, ushort_t* __restrict__ v) {
    __shared__ char alds[2][8192];
    __shared__ char blds[2][8192];
    const int tid = threadIdx.x;
    const int w = tid >> 6, lane = tid & 63;
    const int lr = lane & 15, lg = lane >> 4;
    const int wr = w >> 1, wc = w & 1;
    const int m0 = blockIdx.x * 128;
    const int c0g = blockIdx.y * 128;
    const int z = c0g >> 9;
    const int c0 = c0g & 511;
    const ushort_t* W = wt + (size_t)z * 262144;
    const float* bias = (z == 0) ? bq : (z == 1) ? bk : bv;
    const float scale = (z == 0) ? 0.04419417382415922f : 1.0f;

    f32x4 acc[4][4];
    #pragma unroll
    for (int a = 0; a < 4; ++a)
        #pragma unroll
        for (int b = 0; b < 4; ++b) acc[a][b] = (f32x4){0.f,0.f,0.f,0.f};

    const int g1 = tid, g2 = tid + 256;
    const int r1 = g1 >> 2, s1 = ((g1 & 3) ^ (r1 & 3)) << 4;
    const int r2g = g2 >> 2, s2 = ((g2 & 3) ^ (r2g & 3)) << 4;

    auto STAGE = [&](int buf, int k0) {
        const char* A = (const char*)xn + (size_t)(m0) * 1024 + k0 * 2;
        const char* B = (const char*)W + (size_t)(c0) * 1024 + k0 * 2;
        __builtin_amdgcn_global_load_lds((const __attribute__((address_space(1))) void*)(A + (size_t)r1 * 1024 + s1),
            (__attribute__((address_space(3))) void*)(&alds[buf][g1 * 16]), 16, 0, 0);
        __builtin_amdgcn_global_load_lds((const __attribute__((address_space(1))) void*)(A + (size_t)r2g * 1024 + s2),
            (__attribute__((address_space(3))) void*)(&alds[buf][g2 * 16]), 16, 0, 0);
        __builtin_amdgcn_global_load_lds((const __attribute__((address_space(1))) void*)(B + (size_t)r1 * 1024 + s1),
            (__attribute__((address_space(3))) void*)(&blds[buf][g1 * 16]), 16, 0, 0);
        __builtin_amdgcn_global_load_lds((const __attribute__((address_space(1))) void*)(B + (size_t)r2g * 1024 + s2),
            (__attribute__((address_space(3))) void*)(&blds[buf][g2 * 16]), 16, 0, 0);
    };

    STAGE(0, 0);
    for (int ks = 0; ks < 16; ++ks) {
        const int cur = ks & 1;
        if (ks < 15) {
            STAGE(cur ^ 1, (ks + 1) * 32);
            asm volatile("s_waitcnt vmcnt(4)" ::: "memory");
        } else {
            asm volatile("s_waitcnt vmcnt(0)" ::: "memory");
        }
        __builtin_amdgcn_s_barrier();
        asm volatile("" ::: "memory");
        s16x8 af[4], bf[4];
        #pragma unroll
        for (int mi = 0; mi < 4; ++mi) {
            int row = wr * 64 + mi * 16 + lr;
            af[mi] = *(const s16x8*)(&alds[cur][row * 64 + ((lg ^ (lr & 3)) << 4)]);
        }
        #pragma unroll
        for (int ni = 0; ni < 4; ++ni) {
            int row = wc * 64 + ni * 16 + lr;
            bf[ni] = *(const s16x8*)(&blds[cur][row * 64 + ((lg ^ (lr & 3)) << 4)]);
        }
        #pragma unroll
        for (int mi = 0; mi < 4; ++mi)
            #pragma unroll
            for (int ni = 0; ni < 4; ++ni)
                acc[mi][ni] = __builtin_amdgcn_mfma_f32_16x16x32_bf16(af[mi], bf[ni], acc[mi][ni], 0, 0, 0);
        asm volatile("" ::: "memory");
        __builtin_amdgcn_s_barrier();
    }

    if (z < 2) {
        ushort_t* out = (z == 0) ? q : k;
        #pragma unroll
        for (int ni = 0; ni < 4; ++ni) {
            int cg = c0 + wc * 64 + ni * 16 + lr;
            float bb = bias[cg];
            #pragma unroll
            for (int mi = 0; mi < 4; ++mi) {
                int row = m0 + wr * 64 + mi * 16 + lg * 4;
                #pragma unroll
                for (int r2 = 0; r2 < 4; ++r2)
                    out[(size_t)(row + r2) * 512 + cg] = f2bf((acc[mi][ni][r2] + bb) * scale);
            }
        }
    } else {
        #pragma unroll
        for (int ni = 0; ni < 4; ++ni) {
            int cg = c0 + wc * 64 + ni * 16 + lr;
            float bb = bias[cg];
            #pragma unroll
            for (int mi = 0; mi < 4; ++mi) {
                int row = m0 + wr * 64 + mi * 16 + lg * 4;
                int batch = row >> 12, j = row & 4095;
                ushort4 o;
                o.x = f2bf(acc[mi][ni][0] + bb);
                o.y = f2bf(acc[mi][ni][1] + bb);
                o.z = f2bf(acc[mi][ni][2] + bb);
                o.w = f2bf(acc[mi][ni][3] + bb);
                *(ushort4*)(v + (size_t)batch * (512*4096) + (size_t)cg * 4096 + j) = o;
            }
        }
    }
}

// ---------------- flash attention, c-split 2 + KV-split 2 for 2-blocks/CU occupancy.
// Block = 4 waves, 64 q-rows, 256 channels (acc 64 regs; qf 64). QK^T + softmax duplicated
// across the c-pair (no cross-block comm). Single-buffered LDS 52.5KB. blockIdx.z = js*2+ch.
__global__ __launch_bounds__(256) __attribute__((amdgpu_waves_per_eu(2)))
void attn_kernel(const ushort_t* __restrict__ q, const ushort_t* __restrict__ k,
                 const ushort_t* __restrict__ vt, ushort_t* __restrict__ Op0,
                 ushort_t* __restrict__ Op1, float2* __restrict__ stats2) {
    __shared__ char slds[32768 + 16384 + 4096 + 256];  // K | V(256c) | plds | rlds
    char* vlds = slds + 32768;
    char* plds = slds + 32768 + 16384;
    float* rlds = (float*)(slds + 32768 + 16384 + 4096);
    const int tid = threadIdx.x;
    const int w = tid >> 6, lane = tid & 63;
    const int lr = lane & 15, lg = lane >> 4;
    const int batch = blockIdx.y;
    const int js = blockIdx.z >> 1;
    const int ch = blockIdx.z & 1;
    const int i0 = blockIdx.x * 64;
    const int jbase = js * 2048;
    const char* kb = (const char*)(k  + (size_t)batch * (4096 * 512));
    const char* vb = (const char*)(vt + (size_t)batch * (512 * 4096) + (size_t)ch * 256 * 4096);
    const ushort_t* qb = q + (size_t)batch * (4096 * 512);

    // Q fragments for this wave's 16 q-rows (B-operand of mfma(K,Q))
    s16x8 qf[16];
    {
        const ushort_t* qrow = qb + (size_t)(i0 + w * 16 + lr) * 512 + lg * 8;
        #pragma unroll
        for (int t = 0; t < 16; ++t) qf[t] = *(const s16x8*)(qrow + t * 32);
    }

    f32x4 acc[4][4];   // [c-tile within 64-ch slice][q-group]
    #pragma unroll
    for (int a = 0; a < 4; ++a)
        #pragma unroll
        for (int b = 0; b < 4; ++b) acc[a][b] = (f32x4){0.f,0.f,0.f,0.f};
    float m = -1e30f, s = 0.f;

    const int vswz = ((lane & 3) ^ ((lane >> 3) & 3)) << 4;

    auto STAGE = [&](int j0) {    // absolute j0; single buffer
        const char* gk = kb + (size_t)j0 * 1024;
        #pragma unroll
        for (int r = 0; r < 8; ++r) {
            int row = w * 8 + r;             // row&7 == r
            __builtin_amdgcn_global_load_lds(
                (const __attribute__((address_space(1))) void*)(gk + (size_t)row * 1024 + ((lane ^ r) << 4)),
                (__attribute__((address_space(3))) void*)(slds + row * 1024), 16, 0, 0);
        }
        const char* gv = vb + (size_t)j0 * 2;
        #pragma unroll
        for (int r = 0; r < 4; ++r) {
            int p = w * 4 + r;               // 16 c-row-groups of this block's 256 channels
            int c = p * 16 + (lane >> 2);
            __builtin_amdgcn_global_load_lds(
                (const __attribute__((address_space(1))) void*)(gv + (size_t)c * 8192 + vswz),
                (__attribute__((address_space(3))) void*)(vlds + p * 1024), 16, 0, 0);
        }
    };

    for (int t = 0; t < 64; ++t) {
        STAGE(jbase + t * 32);
        asm volatile("s_waitcnt vmcnt(0)" ::: "memory");
        __builtin_amdgcn_s_barrier();          // barrier A: tile ready, P free
        asm volatile("" ::: "memory");

        // S^T = K_tile . Q^T : two 16x16 j-tiles
        f32x4 sa = {0,0,0,0}, sb = {0,0,0,0};
        #pragma unroll
        for (int tt = 0; tt < 16; ++tt) {
            s16x8 k0f = *(const s16x8*)(slds + lr * 1024        + ((tt*64 + lg*16) ^ ((lr&7)*16)));
            s16x8 k2f = *(const s16x8*)(slds + (16+lr) * 1024   + ((tt*64 + lg*16) ^ ((lr&7)*16)));
            sa = __builtin_amdgcn_mfma_f32_16x16x32_bf16(k0f, qf[tt], sa, 0,0,0);
            sb = __builtin_amdgcn_mfma_f32_16x16x32_bf16(k2f, qf[tt], sb, 0,0,0);
        }
        f32x4 s1 = sa;   // S^T[4*lg+r][i0+16w+lr]
        f32x4 s2 = sb;   // S^T[16+4*lg+r][i0+16w+lr]

        // online softmax (per q-row; reduce over lg via xor 16/32), defer-max THR=8
        float tm = fmaxf(fmaxf(fmaxf(s1[0], s1[1]), fmaxf(s1[2], s1[3])),
                         fmaxf(fmaxf(s2[0], s2[1]), fmaxf(s2[2], s2[3])));
        tm = fmaxf(tm, __shfl_xor(tm, 16));
        tm = fmaxf(tm, __shfl_xor(tm, 32));
        float resc = 1.f;
        if (!__all(tm <= m + 8.f)) {
            float mnew = fmaxf(m, tm);
            resc = __expf(m - mnew);
            s *= resc;
            m = mnew;
        }
        f32x4 p1, p2;
        #pragma unroll
        for (int r2 = 0; r2 < 4; ++r2) { p1[r2] = __expf(s1[r2] - m); p2[r2] = __expf(s2[r2] - m); }
        float ts = p1[0]+p1[1]+p1[2]+p1[3] + p2[0]+p2[1]+p2[2]+p2[3];
        ts += __shfl_xor(ts, 16);
        ts += __shfl_xor(ts, 32);
        s += ts;

        // write P^T for this wave's q-group (g = w) into plds (B-frag layout, XOR by i&3)
        {
            unsigned w0 = (unsigned)f2bf(p1[0]) | ((unsigned)f2bf(p1[1]) << 16);
            unsigned w1 = (unsigned)f2bf(p1[2]) | ((unsigned)f2bf(p1[3]) << 16);
            unsigned w2 = (unsigned)f2bf(p2[0]) | ((unsigned)f2bf(p2[1]) << 16);
            unsigned w3 = (unsigned)f2bf(p2[2]) | ((unsigned)f2bf(p2[3]) << 16);
            char* prow = plds + w * 1024 + lr * 64 + ((lg & 1) << 3);
            *(uint2*)(prow + ((((lg >> 1)    ) ^ (lr & 3)) << 4)) = (uint2){w0, w1};
            *(uint2*)(prow + (((2 | (lg >> 1)) ^ (lr & 3)) << 4)) = (uint2){w2, w3};
            if (lg == 0) rlds[w * 16 + lr] = resc;
        }
        asm volatile("s_waitcnt lgkmcnt(0)" ::: "memory");
        __builtin_amdgcn_s_barrier();          // barrier B: P + resc visible
        asm volatile("" ::: "memory");

        // rescale this wave's O slice
        {
            float rf0 = rlds[lr], rf1 = rlds[16 + lr], rf2 = rlds[32 + lr], rf3 = rlds[48 + lr];
            if (__any(rf0 != 1.f || rf1 != 1.f || rf2 != 1.f || rf3 != 1.f)) {
                #pragma unroll
                for (int ct = 0; ct < 4; ++ct) {
                    acc[ct][0] *= rf0; acc[ct][1] *= rf1; acc[ct][2] *= rf2; acc[ct][3] *= rf3;
                }
            }
        }
        // read the 4 P fragments (one per q-group)
        s16x8 pf[4];
        #pragma unroll
        for (int g = 0; g < 4; ++g)
            pf[g] = *(const s16x8*)(plds + g * 1024 + lr * 64 + ((lg ^ (lr & 3)) << 4));

        // PV: this wave's 64-channel slice x all 4 q-groups
        #pragma unroll
        for (int ct = 0; ct < 4; ++ct) {
            int c = w * 64 + ct * 16 + lr;     // local c within 256
            s16x8 vf = *(const s16x8*)(vlds + c * 64 + ((lg ^ ((lr >> 1) & 3)) << 4));
            #pragma unroll
            for (int g = 0; g < 4; ++g)
                acc[ct][g] = __builtin_amdgcn_mfma_f32_16x16x32_bf16(vf, pf[g], acc[ct][g], 0,0,0);
        }
        asm volatile("" ::: "memory");
        __builtin_amdgcn_s_barrier();          // barrier C: buf/P free for next STAGE
    }

    // stats + final 1/s exchange
    if (lg == 0) {
        rlds[w * 16 + lr] = 1.f / s;
        if (ch == 0)
            stats2[((size_t)(batch * 2 + js)) * 4096 + i0 + w * 16 + lr] = (float2){m, s};
    }
    __syncthreads();
    ushort_t* Op = js ? Op1 : Op0;
    float inv0 = rlds[lr], inv1 = rlds[16 + lr], inv2 = rlds[32 + lr], inv3 = rlds[48 + lr];
    #pragma unroll
    for (int ct = 0; ct < 4; ++ct) {
        #pragma unroll
        for (int g = 0; g < 4; ++g) {
            float iv = (g == 0) ? inv0 : (g == 1) ? inv1 : (g == 2) ? inv2 : inv3;
            ushort4 o;
            o.x = f2bf(acc[ct][g][0] * iv);
            o.y = f2bf(acc[ct][g][1] * iv);
            o.z = f2bf(acc[ct][g][2] * iv);
            o.w = f2bf(acc[ct][g][3] * iv);
            *(ushort4*)(Op + ((size_t)batch * 4096 + i0 + g*16 + lr) * 512
                        + ch * 256 + w * 64 + ct * 16 + lg * 4) = o;
        }
    }
}

// ---------------- flash-combine the two KV-halves, in place into Op0
__global__ void combine_kernel(ushort_t* __restrict__ Op0, const ushort_t* __restrict__ Op1,
                               const float2* __restrict__ stats2) {
    int idx = blockIdx.x * 256 + threadIdx.x;
    int row = idx >> 7;
    int cc = (idx & 127) << 2;
    int b = row >> 12, r = row & 4095;
    float2 st0 = stats2[((size_t)(b * 2 + 0)) * 4096 + r];
    float2 st1 = stats2[((size_t)(b * 2 + 1)) * 4096 + r];
    float M = fmaxf(st0.x, st1.x);
    float w0 = __expf(st0.x - M) * st0.y;
    float w1 = __expf(st1.x - M) * st1.y;
    float rden = 1.f / (w0 + w1);
    w0 *= rden; w1 *= rden;
    size_t off = (size_t)row * 512 + cc;
    ushort4 a = *(ushort4*)(Op0 + off);
    ushort4 c4 = *(const ushort4*)(Op1 + off);
    ushort4 o;
    o.x = f2bf(w0 * bf2f(a.x) + w1 * bf2f(c4.x));
    o.y = f2bf(w0 * bf2f(a.y) + w1 * bf2f(c4.y));
    o.z = f2bf(w0 * bf2f(a.z) + w1 * bf2f(c4.z));
    o.w = f2bf(w0 * bf2f(a.w) + w1 * bf2f(c4.w));
    *(ushort4*)(Op0 + off) = o;
}

// ---------------- final projection, m97-style 128x128 tile + bias + residual (fp32 out)
__global__ __launch_bounds__(256) void proj_kernel(const ushort_t* __restrict__ O, const ushort_t* __restrict__ wt,
                          const float* __restrict__ bp, const float* __restrict__ x, float* __restrict__ out) {
    __shared__ char alds[2][8192];
    __shared__ char blds[2][8192];
    const int tid = threadIdx.x;
    const int w = tid >> 6, lane = tid & 63;
    const int lr = lane & 15, lg = lane >> 4;
    const int wr = w >> 1, wc = w & 1;
    const int m0 = blockIdx.x * 128;
    const int c0 = blockIdx.y * 128;
    const ushort_t* W = wt + (size_t)3 * 262144;

    f32x4 acc[4][4];
    #pragma unroll
    for (int a = 0; a < 4; ++a)
        #pragma unroll
        for (int b = 0; b < 4; ++b) acc[a][b] = (f32x4){0.f,0.f,0.f,0.f};

    const int g1 = tid, g2 = tid + 256;
    const int r1 = g1 >> 2, s1 = ((g1 & 3) ^ (r1 & 3)) << 4;
    const int r2g = g2 >> 2, s2 = ((g2 & 3) ^ (r2g & 3)) << 4;

    auto STAGE = [&](int buf, int k0) {
        const char* A = (const char*)O + (size_t)(m0) * 1024 + k0 * 2;
        const char* B = (const char*)W + (size_t)(c0) * 1024 + k0 * 2;
        __builtin_amdgcn_global_load_lds((const __attribute__((address_space(1))) void*)(A + (size_t)r1 * 1024 + s1),
            (__attribute__((address_space(3))) void*)(&alds[buf][g1 * 16]), 16, 0, 0);
        __builtin_amdgcn_global_load_lds((const __attribute__((address_space(1))) void*)(A + (size_t)r2g * 1024 + s2),
            (__attribute__((address_space(3))) void*)(&alds[buf][g2 * 16]), 16, 0, 0);
        __builtin_amdgcn_global_load_lds((const __attribute__((address_space(1))) void*)(B + (size_t)r1 * 1024 + s1),
            (__attribute__((address_space(3))) void*)(&blds[buf][g1 * 16]), 16, 0, 0);
        __builtin_amdgcn_global_load_lds((const __attribute__((address_space(1))) void*)(B + (size_t)r2g * 1024 + s2),
            (__attribute__((address_space(3))) void*)(&blds[buf][g2 * 16]), 16, 0, 0);
    };

    STAGE(0, 0);
    for (int ks = 0; ks < 16; ++ks) {
        const int cur = ks & 1;
        if (ks < 15) {
            STAGE(cur ^ 1, (ks + 1) * 32);
            asm volatile("s_waitcnt vmcnt(4)" ::: "memory");
        } else {
            asm volatile("s_waitcnt vmcnt(0)" ::: "memory");
        }
        __builtin_amdgcn_s_barrier();
        asm volatile("" ::: "memory");
        s16x8 af[4], bf[4];
        #pragma unroll
        for (int mi = 0; mi < 4; ++mi) {
            int row = wr * 64 + mi * 16 + lr;
            af[mi] = *(const s16x8*)(&alds[cur][row * 64 + ((lg ^ (lr & 3)) << 4)]);
        }
        #pragma unroll
        for (int ni = 0; ni < 4; ++ni) {
            int row = wc * 64 + ni * 16 + lr;
            bf[ni] = *(const s16x8*)(&blds[cur][row * 64 + ((lg ^ (lr & 3)) << 4)]);
        }
        #pragma unroll
        for (int mi = 0; mi < 4; ++mi)
            #pragma unroll
            for (int ni = 0; ni < 4; ++ni)
                acc[mi][ni] = __builtin_amdgcn_mfma_f32_16x16x32_bf16(af[mi], bf[ni], acc[mi][ni], 0, 0, 0);
        asm volatile("" ::: "memory");
        __builtin_amdgcn_s_barrier();
    }

    #pragma unroll
    for (int ni = 0; ni < 4; ++ni) {
        int cg = c0 + wc * 64 + ni * 16 + lr;
        float bb = bp[cg];
        #pragma unroll
        for (int mi = 0; mi < 4; ++mi) {
            int row = m0 + wr * 64 + mi * 16 + lg * 4;
            #pragma unroll
            for (int r2 = 0; r2 < 4; ++r2) {
                size_t idx = (size_t)(row + r2) * 512 + cg;
                out[idx] = acc[mi][ni][r2] + bb + x[idx];
            }
        }
    }
}

extern "C" void kernel_launch(void* const* d_in, const int* in_sizes, int n_in,
                              void* d_out, int out_size, void* d_ws, size_t ws_size,
                              hipStream_t stream) {
    (void)in_sizes; (void)n_in; (void)out_size; (void)ws_size;
    const float* x     = (const float*)d_in[0];
    const float* gamma = (const float*)d_in[1];
    const float* beta  = (const float*)d_in[2];
    const float* wq    = (const float*)d_in[3];
    const float* bq    = (const float*)d_in[4];
    const float* wk    = (const float*)d_in[5];
    const float* bk    = (const float*)d_in[6];
    const float* wv    = (const float*)d_in[7];
    const float* bv    = (const float*)d_in[8];
    const float* wp    = (const float*)d_in[9];
    const float* bp    = (const float*)d_in[10];
    float* out = (float*)d_out;

    char* ws = (char*)d_ws;
    ushort_t* wt    = (ushort_t*)(ws);                 // 2 MB
    float*    stats = (float*)(ws + (2ull<<20));       // 1 KB
    float2*   st2   = (float2*)(ws + (3ull<<20));      // 256 KB
    ushort_t* xn    = (ushort_t*)(ws + (4ull<<20));    // 16 MB (xn; reused as attn partial 1)
    ushort_t* qb    = (ushort_t*)(ws + (20ull<<20));   // 16 MB
    ushort_t* kb    = (ushort_t*)(ws + (36ull<<20));   // 16 MB
    ushort_t* vt    = (ushort_t*)(ws + (52ull<<20));   // 16 MB
    ushort_t* Ob    = (ushort_t*)(ws + (68ull<<20));   // 16 MB

    hipLaunchKernelGGL(wconv_kernel,    dim3(4096),       dim3(256), 0, stream, wq, wk, wv, wp, wt);
    hipLaunchKernelGGL(gn_stats_kernel, dim3(128),        dim3(256), 0, stream, x, stats);
    hipLaunchKernelGGL(gn_norm_kernel,  dim3(8192),       dim3(256), 0, stream, x, gamma, beta, stats, xn);
    hipLaunchKernelGGL(qkv_kernel,      dim3(128, 12),    dim3(256), 0, stream, xn, wt, bq, bk, bv, qb, kb, vt);
    hipLaunchKernelGGL(attn_kernel,     dim3(64, 4, 4),   dim3(256), 0, stream, qb, kb, vt, Ob, xn, st2);
    hipLaunchKernelGGL(combine_kernel,  dim3(8192),       dim3(256), 0, stream, Ob, xn, st2);
    hipLaunchKernelGGL(proj_kernel,     dim3(128, 4),     dim3(256), 0, stream, Ob, wt, bp, x, out);
}

// Round 11
// 359.071 us; speedup vs baseline: 1.1317x; 1.1317x over previous
//
#include <hip/hip_runtime.h>
#include <hip/hip_bf16.h>

typedef __attribute__((ext_vector_type(4))) float f32x4;
typedef __attribute__((ext_vector_type(8))) short s16x8;
typedef unsigned short ushort_t;

#define N_DIM 4096
#define C_DIM 512

static __device__ __forceinline__ unsigned short f2bf(float f) {
    union { float f; unsigned u; } v; v.f = f;
    unsigned r = v.u + 0x7FFFu + ((v.u >> 16) & 1u);
    return (unsigned short)(r >> 16);
}
static __device__ __forceinline__ float bf2f(unsigned short u) {
    union { unsigned u; float f; } v; v.u = ((unsigned)u) << 16;
    return v.f;
}

// ---------------- GroupNorm stats
__global__ void gn_stats_kernel(const float* __restrict__ x, float* __restrict__ stats) {
    int bg = blockIdx.x;
    int b = bg >> 5, g = bg & 31;
    const float* base = x + (size_t)b * (N_DIM * C_DIM) + g * 16;
    float sum = 0.f, ss = 0.f;
    for (int n = threadIdx.x; n < N_DIM; n += 256) {
        const float4* p = (const float4*)(base + (size_t)n * C_DIM);
        #pragma unroll
        for (int t = 0; t < 4; ++t) {
            float4 v = p[t];
            sum += v.x + v.y + v.z + v.w;
            ss  += v.x*v.x + v.y*v.y + v.z*v.z + v.w*v.w;
        }
    }
    #pragma unroll
    for (int o = 32; o > 0; o >>= 1) {
        sum += __shfl_down(sum, o);
        ss  += __shfl_down(ss, o);
    }
    __shared__ float red[8];
    int wid = threadIdx.x >> 6, lane = threadIdx.x & 63;
    if (lane == 0) { red[wid*2] = sum; red[wid*2+1] = ss; }
    __syncthreads();
    if (threadIdx.x == 0) {
        sum = red[0]+red[2]+red[4]+red[6];
        ss  = red[1]+red[3]+red[5]+red[7];
        float mean = sum * (1.f/65536.f);
        float var  = ss  * (1.f/65536.f) - mean*mean;
        stats[bg*2]   = mean;
        stats[bg*2+1] = rsqrtf(var + 1e-5f);
    }
}

// ---------------- normalize + gamma/beta + cast to bf16
__global__ void gn_norm_kernel(const float* __restrict__ x, const float* __restrict__ gamma,
                               const float* __restrict__ beta, const float* __restrict__ stats,
                               ushort_t* __restrict__ xn) {
    size_t i = ((size_t)blockIdx.x * 256 + threadIdx.x) * 4;
    int c = (int)(i & 511);
    int b = (int)(i >> 21);
    int bg = b*32 + (c >> 4);
    float mean = stats[bg*2], rstd = stats[bg*2+1];
    float4 v  = *(const float4*)(x + i);
    float4 ga = *(const float4*)(gamma + c);
    float4 be = *(const float4*)(beta + c);
    ushort4 o;
    o.x = f2bf((v.x - mean) * rstd * ga.x + be.x);
    o.y = f2bf((v.y - mean) * rstd * ga.y + be.y);
    o.z = f2bf((v.z - mean) * rstd * ga.z + be.z);
    o.w = f2bf((v.w - mean) * rstd * ga.w + be.w);
    *(ushort4*)(xn + i) = o;
}

// ---------------- weights: fp32 [Cin][Cout] -> bf16 transposed [Cout][Cin], 4 mats
__global__ void wconv_kernel(const float* __restrict__ wq, const float* __restrict__ wk,
                             const float* __restrict__ wv, const float* __restrict__ wp,
                             ushort_t* __restrict__ wt) {
    int idx = blockIdx.x * 256 + threadIdx.x;
    int m = idx >> 18;
    int r = idx & 262143;
    int ci = r >> 9, co = r & 511;
    const float* w = (m == 0) ? wq : (m == 1) ? wk : (m == 2) ? wv : wp;
    wt[(size_t)m * 262144 + (size_t)co * 512 + ci] = f2bf(w[(size_t)ci * 512 + co]);
}

// ---------------- QKV GEMM, m97-style 128x128 tile (verified R9/R10)
__global__ __launch_bounds__(256) void qkv_kernel(const ushort_t* __restrict__ xn, const ushort_t* __restrict__ wt,
                         const float* __restrict__ bq, const float* __restrict__ bk, const float* __restrict__ bv,
                         ushort_t* __restrict__ q, ushort_t* __restrict__ k, ushort_t* __restrict__ v) {
    __shared__ char alds[2][8192];
    __shared__ char blds[2][8192];
    const int tid = threadIdx.x;
    const int w = tid >> 6, lane = tid & 63;
    const int lr = lane & 15, lg = lane >> 4;
    const int wr = w >> 1, wc = w & 1;
    const int m0 = blockIdx.x * 128;
    const int c0g = blockIdx.y * 128;
    const int z = c0g >> 9;
    const int c0 = c0g & 511;
    const ushort_t* W = wt + (size_t)z * 262144;
    const float* bias = (z == 0) ? bq : (z == 1) ? bk : bv;
    const float scale = (z == 0) ? 0.04419417382415922f : 1.0f;

    f32x4 acc[4][4];
    #pragma unroll
    for (int a = 0; a < 4; ++a)
        #pragma unroll
        for (int b = 0; b < 4; ++b) acc[a][b] = (f32x4){0.f,0.f,0.f,0.f};

    const int g1 = tid, g2 = tid + 256;
    const int r1 = g1 >> 2, s1 = ((g1 & 3) ^ (r1 & 3)) << 4;
    const int r2g = g2 >> 2, s2 = ((g2 & 3) ^ (r2g & 3)) << 4;

    auto STAGE = [&](int buf, int k0) {
        const char* A = (const char*)xn + (size_t)(m0) * 1024 + k0 * 2;
        const char* B = (const char*)W + (size_t)(c0) * 1024 + k0 * 2;
        __builtin_amdgcn_global_load_lds((const __attribute__((address_space(1))) void*)(A + (size_t)r1 * 1024 + s1),
            (__attribute__((address_space(3))) void*)(&alds[buf][g1 * 16]), 16, 0, 0);
        __builtin_amdgcn_global_load_lds((const __attribute__((address_space(1))) void*)(A + (size_t)r2g * 1024 + s2),
            (__attribute__((address_space(3))) void*)(&alds[buf][g2 * 16]), 16, 0, 0);
        __builtin_amdgcn_global_load_lds((const __attribute__((address_space(1))) void*)(B + (size_t)r1 * 1024 + s1),
            (__attribute__((address_space(3))) void*)(&blds[buf][g1 * 16]), 16, 0, 0);
        __builtin_amdgcn_global_load_lds((const __attribute__((address_space(1))) void*)(B + (size_t)r2g * 1024 + s2),
            (__attribute__((address_space(3))) void*)(&blds[buf][g2 * 16]), 16, 0, 0);
    };

    STAGE(0, 0);
    for (int ks = 0; ks < 16; ++ks) {
        const int cur = ks & 1;
        if (ks < 15) {
            STAGE(cur ^ 1, (ks + 1) * 32);
            asm volatile("s_waitcnt vmcnt(4)" ::: "memory");
        } else {
            asm volatile("s_waitcnt vmcnt(0)" ::: "memory");
        }
        __builtin_amdgcn_s_barrier();
        asm volatile("" ::: "memory");
        s16x8 af[4], bf[4];
        #pragma unroll
        for (int mi = 0; mi < 4; ++mi) {
            int row = wr * 64 + mi * 16 + lr;
            af[mi] = *(const s16x8*)(&alds[cur][row * 64 + ((lg ^ (lr & 3)) << 4)]);
        }
        #pragma unroll
        for (int ni = 0; ni < 4; ++ni) {
            int row = wc * 64 + ni * 16 + lr;
            bf[ni] = *(const s16x8*)(&blds[cur][row * 64 + ((lg ^ (lr & 3)) << 4)]);
        }
        #pragma unroll
        for (int mi = 0; mi < 4; ++mi)
            #pragma unroll
            for (int ni = 0; ni < 4; ++ni)
                acc[mi][ni] = __builtin_amdgcn_mfma_f32_16x16x32_bf16(af[mi], bf[ni], acc[mi][ni], 0, 0, 0);
        asm volatile("" ::: "memory");
        __builtin_amdgcn_s_barrier();
    }

    if (z < 2) {
        ushort_t* out = (z == 0) ? q : k;
        #pragma unroll
        for (int ni = 0; ni < 4; ++ni) {
            int cg = c0 + wc * 64 + ni * 16 + lr;
            float bb = bias[cg];
            #pragma unroll
            for (int mi = 0; mi < 4; ++mi) {
                int row = m0 + wr * 64 + mi * 16 + lg * 4;
                #pragma unroll
                for (int r2 = 0; r2 < 4; ++r2)
                    out[(size_t)(row + r2) * 512 + cg] = f2bf((acc[mi][ni][r2] + bb) * scale);
            }
        }
    } else {
        #pragma unroll
        for (int ni = 0; ni < 4; ++ni) {
            int cg = c0 + wc * 64 + ni * 16 + lr;
            float bb = bias[cg];
            #pragma unroll
            for (int mi = 0; mi < 4; ++mi) {
                int row = m0 + wr * 64 + mi * 16 + lg * 4;
                int batch = row >> 12, j = row & 4095;
                ushort4 o;
                o.x = f2bf(acc[mi][ni][0] + bb);
                o.y = f2bf(acc[mi][ni][1] + bb);
                o.z = f2bf(acc[mi][ni][2] + bb);
                o.w = f2bf(acc[mi][ni][3] + bb);
                *(ushort4*)(v + (size_t)batch * (512*4096) + (size_t)cg * 4096 + j) = o;
            }
        }
    }
}

// ---------------- flash attention, cross-tile pipelined: ONE barrier/iter.
// Phase t: stage K(t+2)/V(t+1); rescale+P-frag reads; PV(t) || QK(t+1)+softmax+P(t+1)-write;
// vmcnt(0)+lgkmcnt(0)+barrier (drain lands a full phase after issue -> cheap).
// R9 c-layout: 4 waves x 16 q-rows QK, PV c-split 128c x 64 rows. KV-split 2 + combine.
__global__ __launch_bounds__(256) void attn_kernel(const ushort_t* __restrict__ q, const ushort_t* __restrict__ k,
                          const ushort_t* __restrict__ vt, ushort_t* __restrict__ Op0,
                          ushort_t* __restrict__ Op1, float2* __restrict__ stats2) {
    __shared__ char slds[131072 + 8192 + 512];  // 2x(K32K|V32K) | plds x2 | rlds x2
    char* plds = slds + 131072;
    float* rlds = (float*)(slds + 131072 + 8192);
    const int tid = threadIdx.x;
    const int w = tid >> 6, lane = tid & 63;
    const int lr = lane & 15, lg = lane >> 4;
    const int batch = blockIdx.y;
    const int js = blockIdx.z;
    const int i0 = blockIdx.x * 64;
    const int jbase = js * 2048;
    const char* kb = (const char*)(k  + (size_t)batch * (4096 * 512));
    const char* vb = (const char*)(vt + (size_t)batch * (512 * 4096));
    const ushort_t* qb = q + (size_t)batch * (4096 * 512);

    s16x8 qf[16];
    {
        const ushort_t* qrow = qb + (size_t)(i0 + w * 16 + lr) * 512 + lg * 8;
        #pragma unroll
        for (int t = 0; t < 16; ++t) qf[t] = *(const s16x8*)(qrow + t * 32);
    }

    f32x4 acc[8][4];
    #pragma unroll
    for (int a = 0; a < 8; ++a)
        #pragma unroll
        for (int b = 0; b < 4; ++b) acc[a][b] = (f32x4){0.f,0.f,0.f,0.f};
    float m = -1e30f, s = 0.f;

    const int vswz = ((lane & 3) ^ ((lane >> 3) & 3)) << 4;

    auto STAGE_K = [&](int buf, int j0) {
        char* lb = slds + buf * 65536;
        const char* gk = kb + (size_t)j0 * 1024;
        #pragma unroll
        for (int r = 0; r < 8; ++r) {
            int row = w * 8 + r;             // row&7 == r
            __builtin_amdgcn_global_load_lds(
                (const __attribute__((address_space(1))) void*)(gk + (size_t)row * 1024 + ((lane ^ r) << 4)),
                (__attribute__((address_space(3))) void*)(lb + row * 1024), 16, 0, 0);
        }
    };
    auto STAGE_V = [&](int buf, int j0) {
        char* lv = slds + buf * 65536 + 32768;
        const char* gv = vb + (size_t)j0 * 2;
        #pragma unroll
        for (int r = 0; r < 8; ++r) {
            int p = w * 8 + r;
            int c = p * 16 + (lane >> 2);
            __builtin_amdgcn_global_load_lds(
                (const __attribute__((address_space(1))) void*)(gv + (size_t)c * 8192 + vswz),
                (__attribute__((address_space(3))) void*)(lv + p * 1024), 16, 0, 0);
        }
    };

    // QK(tile from buf) + online softmax + write P/resc into plds[pbuf]/rlds[pbuf]
    auto QKSM = [&](int buf, int pbuf) {
        const char* kl = slds + buf * 65536;
        f32x4 sa = {0,0,0,0}, sb = {0,0,0,0}, sc2 = {0,0,0,0}, sd = {0,0,0,0};
        #pragma unroll
        for (int tt = 0; tt < 16; tt += 2) {
            s16x8 k0f = *(const s16x8*)(kl + lr * 1024        + ((tt*64 + lg*16)     ^ ((lr&7)*16)));
            s16x8 k1f = *(const s16x8*)(kl + lr * 1024        + (((tt+1)*64 + lg*16) ^ ((lr&7)*16)));
            s16x8 k2f = *(const s16x8*)(kl + (16+lr) * 1024   + ((tt*64 + lg*16)     ^ ((lr&7)*16)));
            s16x8 k3f = *(const s16x8*)(kl + (16+lr) * 1024   + (((tt+1)*64 + lg*16) ^ ((lr&7)*16)));
            sa  = __builtin_amdgcn_mfma_f32_16x16x32_bf16(k0f, qf[tt],   sa,  0,0,0);
            sb  = __builtin_amdgcn_mfma_f32_16x16x32_bf16(k1f, qf[tt+1], sb,  0,0,0);
            sc2 = __builtin_amdgcn_mfma_f32_16x16x32_bf16(k2f, qf[tt],   sc2, 0,0,0);
            sd  = __builtin_amdgcn_mfma_f32_16x16x32_bf16(k3f, qf[tt+1], sd,  0,0,0);
        }
        f32x4 s1 = sa + sb;
        f32x4 s2 = sc2 + sd;

        float tm = fmaxf(fmaxf(fmaxf(s1[0], s1[1]), fmaxf(s1[2], s1[3])),
                         fmaxf(fmaxf(s2[0], s2[1]), fmaxf(s2[2], s2[3])));
        tm = fmaxf(tm, __shfl_xor(tm, 16));
        tm = fmaxf(tm, __shfl_xor(tm, 32));
        float resc = 1.f;
        if (!__all(tm <= m + 8.f)) {
            float mnew = fmaxf(m, tm);
            resc = __expf(m - mnew);
            s *= resc;
            m = mnew;
        }
        f32x4 p1, p2;
        #pragma unroll
        for (int r2 = 0; r2 < 4; ++r2) { p1[r2] = __expf(s1[r2] - m); p2[r2] = __expf(s2[r2] - m); }
        float ts = p1[0]+p1[1]+p1[2]+p1[3] + p2[0]+p2[1]+p2[2]+p2[3];
        ts += __shfl_xor(ts, 16);
        ts += __shfl_xor(ts, 32);
        s += ts;

        unsigned w0 = (unsigned)f2bf(p1[0]) | ((unsigned)f2bf(p1[1]) << 16);
        unsigned w1 = (unsigned)f2bf(p1[2]) | ((unsigned)f2bf(p1[3]) << 16);
        unsigned w2 = (unsigned)f2bf(p2[0]) | ((unsigned)f2bf(p2[1]) << 16);
        unsigned w3 = (unsigned)f2bf(p2[2]) | ((unsigned)f2bf(p2[3]) << 16);
        char* prow = plds + pbuf * 4096 + w * 1024 + lr * 64 + ((lg & 1) << 3);
        *(uint2*)(prow + ((((lg >> 1)    ) ^ (lr & 3)) << 4)) = (uint2){w0, w1};
        *(uint2*)(prow + (((2 | (lg >> 1)) ^ (lr & 3)) << 4)) = (uint2){w2, w3};
        if (lg == 0) rlds[pbuf * 64 + w * 16 + lr] = resc;
    };

    // prologue: K(0),V(0) -> buf0; K(1) -> buf1
    STAGE_K(0, jbase);
    STAGE_V(0, jbase);
    STAGE_K(1, jbase + 32);
    asm volatile("s_waitcnt vmcnt(8)" ::: "memory");
    __builtin_amdgcn_s_barrier();
    asm volatile("" ::: "memory");
    QKSM(0, 0);
    asm volatile("s_waitcnt lgkmcnt(0)" ::: "memory");
    __builtin_amdgcn_s_barrier();
    asm volatile("" ::: "memory");

    for (int t = 0; t < 64; ++t) {
        const int cur = t & 1, nxt = cur ^ 1;
        if (t < 62) STAGE_K(cur, jbase + (t + 2) * 32);
        if (t < 63) STAGE_V(nxt, jbase + (t + 1) * 32);

        // rescale + P fragments for tile t (LDS only; data published at last barrier)
        {
            const float* rr = rlds + cur * 64;
            float rf0 = rr[lr], rf1 = rr[16 + lr], rf2 = rr[32 + lr], rf3 = rr[48 + lr];
            if (__any(rf0 != 1.f || rf1 != 1.f || rf2 != 1.f || rf3 != 1.f)) {
                #pragma unroll
                for (int ct = 0; ct < 8; ++ct) {
                    acc[ct][0] *= rf0; acc[ct][1] *= rf1; acc[ct][2] *= rf2; acc[ct][3] *= rf3;
                }
            }
        }
        s16x8 pf[4];
        #pragma unroll
        for (int g = 0; g < 4; ++g)
            pf[g] = *(const s16x8*)(plds + cur * 4096 + g * 1024 + lr * 64 + ((lg ^ (lr & 3)) << 4));

        // PV(t): this wave's 128-channel quarter x all 4 q-groups (V from buf[cur])
        const char* vl = slds + cur * 65536 + 32768;
        #pragma unroll
        for (int ct = 0; ct < 8; ++ct) {
            int c = w * 128 + ct * 16 + lr;
            s16x8 vf = *(const s16x8*)(vl + c * 64 + ((lg ^ ((lr >> 1) & 3)) << 4));
            #pragma unroll
            for (int g = 0; g < 4; ++g)
                acc[ct][g] = __builtin_amdgcn_mfma_f32_16x16x32_bf16(vf, pf[g], acc[ct][g], 0,0,0);
        }

        // QK(t+1) + softmax + P(t+1) publish (independent of PV -> interleaves)
        if (t < 63) QKSM(nxt, nxt);

        asm volatile("s_waitcnt vmcnt(0) lgkmcnt(0)" ::: "memory");
        __builtin_amdgcn_s_barrier();
        asm volatile("" ::: "memory");
    }

    // stats + final 1/s exchange (rlds region 0; loop's final barrier freed it)
    if (lg == 0) {
        rlds[w * 16 + lr] = 1.f / s;
        stats2[((size_t)(batch * 2 + js)) * 4096 + i0 + w * 16 + lr] = (float2){m, s};
    }
    __syncthreads();
    ushort_t* Op = js ? Op1 : Op0;
    float inv0 = rlds[lr], inv1 = rlds[16 + lr], inv2 = rlds[32 + lr], inv3 = rlds[48 + lr];
    #pragma unroll
    for (int ct = 0; ct < 8; ++ct) {
        #pragma unroll
        for (int g = 0; g < 4; ++g) {
            float iv = (g == 0) ? inv0 : (g == 1) ? inv1 : (g == 2) ? inv2 : inv3;
            ushort4 o;
            o.x = f2bf(acc[ct][g][0] * iv);
            o.y = f2bf(acc[ct][g][1] * iv);
            o.z = f2bf(acc[ct][g][2] * iv);
            o.w = f2bf(acc[ct][g][3] * iv);
            *(ushort4*)(Op + ((size_t)batch * 4096 + i0 + g*16 + lr) * 512
                        + w * 128 + ct * 16 + lg * 4) = o;
        }
    }
}

// ---------------- flash-combine the two KV-halves, in place into Op0
__global__ void combine_kernel(ushort_t* __restrict__ Op0, const ushort_t* __restrict__ Op1,
                               const float2* __restrict__ stats2) {
    int idx = blockIdx.x * 256 + threadIdx.x;
    int row = idx >> 7;
    int cc = (idx & 127) << 2;
    int b = row >> 12, r = row & 4095;
    float2 st0 = stats2[((size_t)(b * 2 + 0)) * 4096 + r];
    float2 st1 = stats2[((size_t)(b * 2 + 1)) * 4096 + r];
    float M = fmaxf(st0.x, st1.x);
    float w0 = __expf(st0.x - M) * st0.y;
    float w1 = __expf(st1.x - M) * st1.y;
    float rden = 1.f / (w0 + w1);
    w0 *= rden; w1 *= rden;
    size_t off = (size_t)row * 512 + cc;
    ushort4 a = *(ushort4*)(Op0 + off);
    ushort4 c4 = *(const ushort4*)(Op1 + off);
    ushort4 o;
    o.x = f2bf(w0 * bf2f(a.x) + w1 * bf2f(c4.x));
    o.y = f2bf(w0 * bf2f(a.y) + w1 * bf2f(c4.y));
    o.z = f2bf(w0 * bf2f(a.z) + w1 * bf2f(c4.z));
    o.w = f2bf(w0 * bf2f(a.w) + w1 * bf2f(c4.w));
    *(ushort4*)(Op0 + off) = o;
}

// ---------------- final projection, m97-style 128x128 tile + bias + residual (fp32 out)
__global__ __launch_bounds__(256) void proj_kernel(const ushort_t* __restrict__ O, const ushort_t* __restrict__ wt,
                          const float* __restrict__ bp, const float* __restrict__ x, float* __restrict__ out) {
    __shared__ char alds[2][8192];
    __shared__ char blds[2][8192];
    const int tid = threadIdx.x;
    const int w = tid >> 6, lane = tid & 63;
    const int lr = lane & 15, lg = lane >> 4;
    const int wr = w >> 1, wc = w & 1;
    const int m0 = blockIdx.x * 128;
    const int c0 = blockIdx.y * 128;
    const ushort_t* W = wt + (size_t)3 * 262144;

    f32x4 acc[4][4];
    #pragma unroll
    for (int a = 0; a < 4; ++a)
        #pragma unroll
        for (int b = 0; b < 4; ++b) acc[a][b] = (f32x4){0.f,0.f,0.f,0.f};

    const int g1 = tid, g2 = tid + 256;
    const int r1 = g1 >> 2, s1 = ((g1 & 3) ^ (r1 & 3)) << 4;
    const int r2g = g2 >> 2, s2 = ((g2 & 3) ^ (r2g & 3)) << 4;

    auto STAGE = [&](int buf, int k0) {
        const char* A = (const char*)O + (size_t)(m0) * 1024 + k0 * 2;
        const char* B = (const char*)W + (size_t)(c0) * 1024 + k0 * 2;
        __builtin_amdgcn_global_load_lds((const __attribute__((address_space(1))) void*)(A + (size_t)r1 * 1024 + s1),
            (__attribute__((address_space(3))) void*)(&alds[buf][g1 * 16]), 16, 0, 0);
        __builtin_amdgcn_global_load_lds((const __attribute__((address_space(1))) void*)(A + (size_t)r2g * 1024 + s2),
            (__attribute__((address_space(3))) void*)(&alds[buf][g2 * 16]), 16, 0, 0);
        __builtin_amdgcn_global_load_lds((const __attribute__((address_space(1))) void*)(B + (size_t)r1 * 1024 + s1),
            (__attribute__((address_space(3))) void*)(&blds[buf][g1 * 16]), 16, 0, 0);
        __builtin_amdgcn_global_load_lds((const __attribute__((address_space(1))) void*)(B + (size_t)r2g * 1024 + s2),
            (__attribute__((address_space(3))) void*)(&blds[buf][g2 * 16]), 16, 0, 0);
    };

    STAGE(0, 0);
    for (int ks = 0; ks < 16; ++ks) {
        const int cur = ks & 1;
        if (ks < 15) {
            STAGE(cur ^ 1, (ks + 1) * 32);
            asm volatile("s_waitcnt vmcnt(4)" ::: "memory");
        } else {
            asm volatile("s_waitcnt vmcnt(0)" ::: "memory");
        }
        __builtin_amdgcn_s_barrier();
        asm volatile("" ::: "memory");
        s16x8 af[4], bf[4];
        #pragma unroll
        for (int mi = 0; mi < 4; ++mi) {
            int row = wr * 64 + mi * 16 + lr;
            af[mi] = *(const s16x8*)(&alds[cur][row * 64 + ((lg ^ (lr & 3)) << 4)]);
        }
        #pragma unroll
        for (int ni = 0; ni < 4; ++ni) {
            int row = wc * 64 + ni * 16 + lr;
            bf[ni] = *(const s16x8*)(&blds[cur][row * 64 + ((lg ^ (lr & 3)) << 4)]);
        }
        #pragma unroll
        for (int mi = 0; mi < 4; ++mi)
            #pragma unroll
            for (int ni = 0; ni < 4; ++ni)
                acc[mi][ni] = __builtin_amdgcn_mfma_f32_16x16x32_bf16(af[mi], bf[ni], acc[mi][ni], 0, 0, 0);
        asm volatile("" ::: "memory");
        __builtin_amdgcn_s_barrier();
    }

    #pragma unroll
    for (int ni = 0; ni < 4; ++ni) {
        int cg = c0 + wc * 64 + ni * 16 + lr;
        float bb = bp[cg];
        #pragma unroll
        for (int mi = 0; mi < 4; ++mi) {
            int row = m0 + wr * 64 + mi * 16 + lg * 4;
            #pragma unroll
            for (int r2 = 0; r2 < 4; ++r2) {
                size_t idx = (size_t)(row + r2) * 512 + cg;
                out[idx] = acc[mi][ni][r2] + bb + x[idx];
            }
        }
    }
}

extern "C" void kernel_launch(void* const* d_in, const int* in_sizes, int n_in,
                              void* d_out, int out_size, void* d_ws, size_t ws_size,
                              hipStream_t stream) {
    (void)in_sizes; (void)n_in; (void)out_size; (void)ws_size;
    const float* x     = (const float*)d_in[0];
    const float* gamma = (const float*)d_in[1];
    const float* beta  = (const float*)d_in[2];
    const float* wq    = (const float*)d_in[3];
    const float* bq    = (const float*)d_in[4];
    const float* wk    = (const float*)d_in[5];
    const float* bk    = (const float*)d_in[6];
    const float* wv    = (const float*)d_in[7];
    const float* bv    = (const float*)d_in[8];
    const float* wp    = (const float*)d_in[9];
    const float* bp    = (const float*)d_in[10];
    float* out = (float*)d_out;

    char* ws = (char*)d_ws;
    ushort_t* wt    = (ushort_t*)(ws);                 // 2 MB
    float*    stats = (float*)(ws + (2ull<<20));       // 1 KB
    float2*   st2   = (float2*)(ws + (3ull<<20));      // 256 KB
    ushort_t* xn    = (ushort_t*)(ws + (4ull<<20));    // 16 MB (xn; reused as attn partial 1)
    ushort_t* qb    = (ushort_t*)(ws + (20ull<<20));   // 16 MB
    ushort_t* kb    = (ushort_t*)(ws + (36ull<<20));   // 16 MB
    ushort_t* vt    = (ushort_t*)(ws + (52ull<<20));   // 16 MB
    ushort_t* Ob    = (ushort_t*)(ws + (68ull<<20));   // 16 MB

    hipLaunchKernelGGL(wconv_kernel,    dim3(4096),       dim3(256), 0, stream, wq, wk, wv, wp, wt);
    hipLaunchKernelGGL(gn_stats_kernel, dim3(128),        dim3(256), 0, stream, x, stats);
    hipLaunchKernelGGL(gn_norm_kernel,  dim3(8192),       dim3(256), 0, stream, x, gamma, beta, stats, xn);
    hipLaunchKernelGGL(qkv_kernel,      dim3(128, 12),    dim3(256), 0, stream, xn, wt, bq, bk, bv, qb, kb, vt);
    hipLaunchKernelGGL(attn_kernel,     dim3(64, 4, 2),   dim3(256), 0, stream, qb, kb, vt, Ob, xn, st2);
    hipLaunchKernelGGL(combine_kernel,  dim3(8192),       dim3(256), 0, stream, Ob, xn, st2);
    hipLaunchKernelGGL(proj_kernel,     dim3(128, 4),     dim3(256), 0, stream, Ob, wt, bp, x, out);
}

// Round 12
// 341.357 us; speedup vs baseline: 1.1905x; 1.0519x over previous
//
#include <hip/hip_runtime.h>
#include <hip/hip_bf16.h>

typedef __attribute__((ext_vector_type(4))) float f32x4;
typedef __attribute__((ext_vector_type(8))) short s16x8;
typedef unsigned short ushort_t;

#define N_DIM 4096
#define C_DIM 512

static __device__ __forceinline__ unsigned short f2bf(float f) {
    union { float f; unsigned u; } v; v.f = f;
    unsigned r = v.u + 0x7FFFu + ((v.u >> 16) & 1u);
    return (unsigned short)(r >> 16);
}

// ---------------- GroupNorm stats
__global__ void gn_stats_kernel(const float* __restrict__ x, float* __restrict__ stats) {
    int bg = blockIdx.x;
    int b = bg >> 5, g = bg & 31;
    const float* base = x + (size_t)b * (N_DIM * C_DIM) + g * 16;
    float sum = 0.f, ss = 0.f;
    for (int n = threadIdx.x; n < N_DIM; n += 256) {
        const float4* p = (const float4*)(base + (size_t)n * C_DIM);
        #pragma unroll
        for (int t = 0; t < 4; ++t) {
            float4 v = p[t];
            sum += v.x + v.y + v.z + v.w;
            ss  += v.x*v.x + v.y*v.y + v.z*v.z + v.w*v.w;
        }
    }
    #pragma unroll
    for (int o = 32; o > 0; o >>= 1) {
        sum += __shfl_down(sum, o);
        ss  += __shfl_down(ss, o);
    }
    __shared__ float red[8];
    int wid = threadIdx.x >> 6, lane = threadIdx.x & 63;
    if (lane == 0) { red[wid*2] = sum; red[wid*2+1] = ss; }
    __syncthreads();
    if (threadIdx.x == 0) {
        sum = red[0]+red[2]+red[4]+red[6];
        ss  = red[1]+red[3]+red[5]+red[7];
        float mean = sum * (1.f/65536.f);
        float var  = ss  * (1.f/65536.f) - mean*mean;
        stats[bg*2]   = mean;
        stats[bg*2+1] = rsqrtf(var + 1e-5f);
    }
}

// ---------------- normalize + gamma/beta + cast to bf16
__global__ void gn_norm_kernel(const float* __restrict__ x, const float* __restrict__ gamma,
                               const float* __restrict__ beta, const float* __restrict__ stats,
                               ushort_t* __restrict__ xn) {
    size_t i = ((size_t)blockIdx.x * 256 + threadIdx.x) * 4;
    int c = (int)(i & 511);
    int b = (int)(i >> 21);
    int bg = b*32 + (c >> 4);
    float mean = stats[bg*2], rstd = stats[bg*2+1];
    float4 v  = *(const float4*)(x + i);
    float4 ga = *(const float4*)(gamma + c);
    float4 be = *(const float4*)(beta + c);
    ushort4 o;
    o.x = f2bf((v.x - mean) * rstd * ga.x + be.x);
    o.y = f2bf((v.y - mean) * rstd * ga.y + be.y);
    o.z = f2bf((v.z - mean) * rstd * ga.z + be.z);
    o.w = f2bf((v.w - mean) * rstd * ga.w + be.w);
    *(ushort4*)(xn + i) = o;
}

// ---------------- weights: fp32 [Cin][Cout] -> bf16 transposed [Cout][Cin], 4 mats
__global__ void wconv_kernel(const float* __restrict__ wq, const float* __restrict__ wk,
                             const float* __restrict__ wv, const float* __restrict__ wp,
                             ushort_t* __restrict__ wt) {
    int idx = blockIdx.x * 256 + threadIdx.x;
    int m = idx >> 18;
    int r = idx & 262143;
    int ci = r >> 9, co = r & 511;
    const float* w = (m == 0) ? wq : (m == 1) ? wk : (m == 2) ? wv : wp;
    wt[(size_t)m * 262144 + (size_t)co * 512 + ci] = f2bf(w[(size_t)ci * 512 + co]);
}

// ---------------- QKV GEMM, m97-style 128x128 tile (verified R9/R10/R11)
__global__ __launch_bounds__(256) void qkv_kernel(const ushort_t* __restrict__ xn, const ushort_t* __restrict__ wt,
                         const float* __restrict__ bq, const float* __restrict__ bk, const float* __restrict__ bv,
                         ushort_t* __restrict__ q, ushort_t* __restrict__ k, ushort_t* __restrict__ v) {
    __shared__ char alds[2][8192];
    __shared__ char blds[2][8192];
    const int tid = threadIdx.x;
    const int w = tid >> 6, lane = tid & 63;
    const int lr = lane & 15, lg = lane >> 4;
    const int wr = w >> 1, wc = w & 1;
    const int m0 = blockIdx.x * 128;
    const int c0g = blockIdx.y * 128;
    const int z = c0g >> 9;
    const int c0 = c0g & 511;
    const ushort_t* W = wt + (size_t)z * 262144;
    const float* bias = (z == 0) ? bq : (z == 1) ? bk : bv;
    const float scale = (z == 0) ? 0.04419417382415922f : 1.0f;

    f32x4 acc[4][4];
    #pragma unroll
    for (int a = 0; a < 4; ++a)
        #pragma unroll
        for (int b = 0; b < 4; ++b) acc[a][b] = (f32x4){0.f,0.f,0.f,0.f};

    const int g1 = tid, g2 = tid + 256;
    const int r1 = g1 >> 2, s1 = ((g1 & 3) ^ (r1 & 3)) << 4;
    const int r2g = g2 >> 2, s2 = ((g2 & 3) ^ (r2g & 3)) << 4;

    auto STAGE = [&](int buf, int k0) {
        const char* A = (const char*)xn + (size_t)(m0) * 1024 + k0 * 2;
        const char* B = (const char*)W + (size_t)(c0) * 1024 + k0 * 2;
        __builtin_amdgcn_global_load_lds((const __attribute__((address_space(1))) void*)(A + (size_t)r1 * 1024 + s1),
            (__attribute__((address_space(3))) void*)(&alds[buf][g1 * 16]), 16, 0, 0);
        __builtin_amdgcn_global_load_lds((const __attribute__((address_space(1))) void*)(A + (size_t)r2g * 1024 + s2),
            (__attribute__((address_space(3))) void*)(&alds[buf][g2 * 16]), 16, 0, 0);
        __builtin_amdgcn_global_load_lds((const __attribute__((address_space(1))) void*)(B + (size_t)r1 * 1024 + s1),
            (__attribute__((address_space(3))) void*)(&blds[buf][g1 * 16]), 16, 0, 0);
        __builtin_amdgcn_global_load_lds((const __attribute__((address_space(1))) void*)(B + (size_t)r2g * 1024 + s2),
            (__attribute__((address_space(3))) void*)(&blds[buf][g2 * 16]), 16, 0, 0);
    };

    STAGE(0, 0);
    for (int ks = 0; ks < 16; ++ks) {
        const int cur = ks & 1;
        if (ks < 15) {
            STAGE(cur ^ 1, (ks + 1) * 32);
            asm volatile("s_waitcnt vmcnt(4)" ::: "memory");
        } else {
            asm volatile("s_waitcnt vmcnt(0)" ::: "memory");
        }
        __builtin_amdgcn_s_barrier();
        asm volatile("" ::: "memory");
        s16x8 af[4], bf[4];
        #pragma unroll
        for (int mi = 0; mi < 4; ++mi) {
            int row = wr * 64 + mi * 16 + lr;
            af[mi] = *(const s16x8*)(&alds[cur][row * 64 + ((lg ^ (lr & 3)) << 4)]);
        }
        #pragma unroll
        for (int ni = 0; ni < 4; ++ni) {
            int row = wc * 64 + ni * 16 + lr;
            bf[ni] = *(const s16x8*)(&blds[cur][row * 64 + ((lg ^ (lr & 3)) << 4)]);
        }
        #pragma unroll
        for (int mi = 0; mi < 4; ++mi)
            #pragma unroll
            for (int ni = 0; ni < 4; ++ni)
                acc[mi][ni] = __builtin_amdgcn_mfma_f32_16x16x32_bf16(af[mi], bf[ni], acc[mi][ni], 0, 0, 0);
        asm volatile("" ::: "memory");
        __builtin_amdgcn_s_barrier();
    }

    if (z < 2) {
        ushort_t* out = (z == 0) ? q : k;
        #pragma unroll
        for (int ni = 0; ni < 4; ++ni) {
            int cg = c0 + wc * 64 + ni * 16 + lr;
            float bb = bias[cg];
            #pragma unroll
            for (int mi = 0; mi < 4; ++mi) {
                int row = m0 + wr * 64 + mi * 16 + lg * 4;
                #pragma unroll
                for (int r2 = 0; r2 < 4; ++r2)
                    out[(size_t)(row + r2) * 512 + cg] = f2bf((acc[mi][ni][r2] + bb) * scale);
            }
        }
    } else {
        #pragma unroll
        for (int ni = 0; ni < 4; ++ni) {
            int cg = c0 + wc * 64 + ni * 16 + lr;
            float bb = bias[cg];
            #pragma unroll
            for (int mi = 0; mi < 4; ++mi) {
                int row = m0 + wr * 64 + mi * 16 + lg * 4;
                int batch = row >> 12, j = row & 4095;
                ushort4 o;
                o.x = f2bf(acc[mi][ni][0] + bb);
                o.y = f2bf(acc[mi][ni][1] + bb);
                o.z = f2bf(acc[mi][ni][2] + bb);
                o.w = f2bf(acc[mi][ni][3] + bb);
                *(ushort4*)(v + (size_t)batch * (512*4096) + (size_t)cg * 4096 + j) = o;
            }
        }
    }
}

// ---------------- flash attention, cross-tile pipelined, ONE barrier/iter, no KV-split.
// Phase t: stage K(t+2)/V(t+1); QK(t+1)+softmax+P(t+1)-publish (long chain first);
// rescale+P-read+PV(t) (independent MFMAs fill the softmax tail); drain+barrier.
__global__ __launch_bounds__(256) void attn_kernel(const ushort_t* __restrict__ q, const ushort_t* __restrict__ k,
                          const ushort_t* __restrict__ vt, ushort_t* __restrict__ O) {
    __shared__ char slds[131072 + 8192 + 512];  // 2x(K32K|V32K) | plds x2 | rlds x2
    char* plds = slds + 131072;
    float* rlds = (float*)(slds + 131072 + 8192);
    const int tid = threadIdx.x;
    const int w = tid >> 6, lane = tid & 63;
    const int lr = lane & 15, lg = lane >> 4;
    const int batch = blockIdx.y;
    const int i0 = blockIdx.x * 64;
    const char* kb = (const char*)(k  + (size_t)batch * (4096 * 512));
    const char* vb = (const char*)(vt + (size_t)batch * (512 * 4096));
    const ushort_t* qb = q + (size_t)batch * (4096 * 512);

    s16x8 qf[16];
    {
        const ushort_t* qrow = qb + (size_t)(i0 + w * 16 + lr) * 512 + lg * 8;
        #pragma unroll
        for (int t = 0; t < 16; ++t) qf[t] = *(const s16x8*)(qrow + t * 32);
    }

    f32x4 acc[8][4];
    #pragma unroll
    for (int a = 0; a < 8; ++a)
        #pragma unroll
        for (int b = 0; b < 4; ++b) acc[a][b] = (f32x4){0.f,0.f,0.f,0.f};
    float m = -1e30f, s = 0.f;

    const int vswz = ((lane & 3) ^ ((lane >> 3) & 3)) << 4;

    auto STAGE_K = [&](int buf, int j0) {
        char* lb = slds + buf * 65536;
        const char* gk = kb + (size_t)j0 * 1024;
        #pragma unroll
        for (int r = 0; r < 8; ++r) {
            int row = w * 8 + r;             // row&7 == r
            __builtin_amdgcn_global_load_lds(
                (const __attribute__((address_space(1))) void*)(gk + (size_t)row * 1024 + ((lane ^ r) << 4)),
                (__attribute__((address_space(3))) void*)(lb + row * 1024), 16, 0, 0);
        }
    };
    auto STAGE_V = [&](int buf, int j0) {
        char* lv = slds + buf * 65536 + 32768;
        const char* gv = vb + (size_t)j0 * 2;
        #pragma unroll
        for (int r = 0; r < 8; ++r) {
            int p = w * 8 + r;
            int c = p * 16 + (lane >> 2);
            __builtin_amdgcn_global_load_lds(
                (const __attribute__((address_space(1))) void*)(gv + (size_t)c * 8192 + vswz),
                (__attribute__((address_space(3))) void*)(lv + p * 1024), 16, 0, 0);
        }
    };

    auto QKSM = [&](int buf, int pbuf) {
        const char* kl = slds + buf * 65536;
        f32x4 sa = {0,0,0,0}, sb = {0,0,0,0}, sc2 = {0,0,0,0}, sd = {0,0,0,0};
        #pragma unroll
        for (int tt = 0; tt < 16; tt += 2) {
            s16x8 k0f = *(const s16x8*)(kl + lr * 1024        + ((tt*64 + lg*16)     ^ ((lr&7)*16)));
            s16x8 k1f = *(const s16x8*)(kl + lr * 1024        + (((tt+1)*64 + lg*16) ^ ((lr&7)*16)));
            s16x8 k2f = *(const s16x8*)(kl + (16+lr) * 1024   + ((tt*64 + lg*16)     ^ ((lr&7)*16)));
            s16x8 k3f = *(const s16x8*)(kl + (16+lr) * 1024   + (((tt+1)*64 + lg*16) ^ ((lr&7)*16)));
            sa  = __builtin_amdgcn_mfma_f32_16x16x32_bf16(k0f, qf[tt],   sa,  0,0,0);
            sb  = __builtin_amdgcn_mfma_f32_16x16x32_bf16(k1f, qf[tt+1], sb,  0,0,0);
            sc2 = __builtin_amdgcn_mfma_f32_16x16x32_bf16(k2f, qf[tt],   sc2, 0,0,0);
            sd  = __builtin_amdgcn_mfma_f32_16x16x32_bf16(k3f, qf[tt+1], sd,  0,0,0);
        }
        f32x4 s1 = sa + sb;
        f32x4 s2 = sc2 + sd;

        float tm = fmaxf(fmaxf(fmaxf(s1[0], s1[1]), fmaxf(s1[2], s1[3])),
                         fmaxf(fmaxf(s2[0], s2[1]), fmaxf(s2[2], s2[3])));
        tm = fmaxf(tm, __shfl_xor(tm, 16));
        tm = fmaxf(tm, __shfl_xor(tm, 32));
        float resc = 1.f;
        if (!__all(tm <= m + 8.f)) {
            float mnew = fmaxf(m, tm);
            resc = __expf(m - mnew);
            s *= resc;
            m = mnew;
        }
        f32x4 p1, p2;
        #pragma unroll
        for (int r2 = 0; r2 < 4; ++r2) { p1[r2] = __expf(s1[r2] - m); p2[r2] = __expf(s2[r2] - m); }
        float ts = p1[0]+p1[1]+p1[2]+p1[3] + p2[0]+p2[1]+p2[2]+p2[3];
        ts += __shfl_xor(ts, 16);
        ts += __shfl_xor(ts, 32);
        s += ts;

        unsigned w0 = (unsigned)f2bf(p1[0]) | ((unsigned)f2bf(p1[1]) << 16);
        unsigned w1 = (unsigned)f2bf(p1[2]) | ((unsigned)f2bf(p1[3]) << 16);
        unsigned w2 = (unsigned)f2bf(p2[0]) | ((unsigned)f2bf(p2[1]) << 16);
        unsigned w3 = (unsigned)f2bf(p2[2]) | ((unsigned)f2bf(p2[3]) << 16);
        char* prow = plds + pbuf * 4096 + w * 1024 + lr * 64 + ((lg & 1) << 3);
        *(uint2*)(prow + ((((lg >> 1)    ) ^ (lr & 3)) << 4)) = (uint2){w0, w1};
        *(uint2*)(prow + (((2 | (lg >> 1)) ^ (lr & 3)) << 4)) = (uint2){w2, w3};
        if (lg == 0) rlds[pbuf * 64 + w * 16 + lr] = resc;
    };

    // prologue: K(0),V(0) -> buf0; K(1) -> buf1; FULL drain (K(1) consumed next phase)
    STAGE_K(0, 0);
    STAGE_V(0, 0);
    STAGE_K(1, 32);
    asm volatile("s_waitcnt vmcnt(0)" ::: "memory");
    __builtin_amdgcn_s_barrier();
    asm volatile("" ::: "memory");
    QKSM(0, 0);
    asm volatile("s_waitcnt lgkmcnt(0)" ::: "memory");
    __builtin_amdgcn_s_barrier();
    asm volatile("" ::: "memory");

    for (int t = 0; t < 128; ++t) {
        const int cur = t & 1, nxt = cur ^ 1;
        if (t < 126) STAGE_K(cur, (t + 2) * 32);
        if (t < 127) STAGE_V(nxt, (t + 1) * 32);

        // QK(t+1) + softmax + P(t+1) publish FIRST (long serial chain starts early)
        if (t < 127) QKSM(nxt, nxt);

        // rescale + P fragments + PV(t) (independent MFMAs overlap softmax tail)
        {
            const float* rr = rlds + cur * 64;
            float rf0 = rr[lr], rf1 = rr[16 + lr], rf2 = rr[32 + lr], rf3 = rr[48 + lr];
            if (__any(rf0 != 1.f || rf1 != 1.f || rf2 != 1.f || rf3 != 1.f)) {
                #pragma unroll
                for (int ct = 0; ct < 8; ++ct) {
                    acc[ct][0] *= rf0; acc[ct][1] *= rf1; acc[ct][2] *= rf2; acc[ct][3] *= rf3;
                }
            }
        }
        s16x8 pf[4];
        #pragma unroll
        for (int g = 0; g < 4; ++g)
            pf[g] = *(const s16x8*)(plds + cur * 4096 + g * 1024 + lr * 64 + ((lg ^ (lr & 3)) << 4));

        const char* vl = slds + cur * 65536 + 32768;
        #pragma unroll
        for (int ct = 0; ct < 8; ++ct) {
            int c = w * 128 + ct * 16 + lr;
            s16x8 vf = *(const s16x8*)(vl + c * 64 + ((lg ^ ((lr >> 1) & 3)) << 4));
            #pragma unroll
            for (int g = 0; g < 4; ++g)
                acc[ct][g] = __builtin_amdgcn_mfma_f32_16x16x32_bf16(vf, pf[g], acc[ct][g], 0,0,0);
        }

        asm volatile("s_waitcnt vmcnt(0) lgkmcnt(0)" ::: "memory");
        __builtin_amdgcn_s_barrier();
        asm volatile("" ::: "memory");
    }

    // final 1/s exchange (rlds region 0 free after last barrier)
    if (lg == 0) rlds[w * 16 + lr] = 1.f / s;
    __syncthreads();
    float inv0 = rlds[lr], inv1 = rlds[16 + lr], inv2 = rlds[32 + lr], inv3 = rlds[48 + lr];
    #pragma unroll
    for (int ct = 0; ct < 8; ++ct) {
        #pragma unroll
        for (int g = 0; g < 4; ++g) {
            float iv = (g == 0) ? inv0 : (g == 1) ? inv1 : (g == 2) ? inv2 : inv3;
            ushort4 o;
            o.x = f2bf(acc[ct][g][0] * iv);
            o.y = f2bf(acc[ct][g][1] * iv);
            o.z = f2bf(acc[ct][g][2] * iv);
            o.w = f2bf(acc[ct][g][3] * iv);
            *(ushort4*)(O + ((size_t)batch * 4096 + i0 + g*16 + lr) * 512
                        + w * 128 + ct * 16 + lg * 4) = o;
        }
    }
}

// ---------------- final projection, m97-style 128x128 tile + bias + residual (fp32 out)
__global__ __launch_bounds__(256) void proj_kernel(const ushort_t* __restrict__ O, const ushort_t* __restrict__ wt,
                          const float* __restrict__ bp, const float* __restrict__ x, float* __restrict__ out) {
    __shared__ char alds[2][8192];
    __shared__ char blds[2][8192];
    const int tid = threadIdx.x;
    const int w = tid >> 6, lane = tid & 63;
    const int lr = lane & 15, lg = lane >> 4;
    const int wr = w >> 1, wc = w & 1;
    const int m0 = blockIdx.x * 128;
    const int c0 = blockIdx.y * 128;
    const ushort_t* W = wt + (size_t)3 * 262144;

    f32x4 acc[4][4];
    #pragma unroll
    for (int a = 0; a < 4; ++a)
        #pragma unroll
        for (int b = 0; b < 4; ++b) acc[a][b] = (f32x4){0.f,0.f,0.f,0.f};

    const int g1 = tid, g2 = tid + 256;
    const int r1 = g1 >> 2, s1 = ((g1 & 3) ^ (r1 & 3)) << 4;
    const int r2g = g2 >> 2, s2 = ((g2 & 3) ^ (r2g & 3)) << 4;

    auto STAGE = [&](int buf, int k0) {
        const char* A = (const char*)O + (size_t)(m0) * 1024 + k0 * 2;
        const char* B = (const char*)W + (size_t)(c0) * 1024 + k0 * 2;
        __builtin_amdgcn_global_load_lds((const __attribute__((address_space(1))) void*)(A + (size_t)r1 * 1024 + s1),
            (__attribute__((address_space(3))) void*)(&alds[buf][g1 * 16]), 16, 0, 0);
        __builtin_amdgcn_global_load_lds((const __attribute__((address_space(1))) void*)(A + (size_t)r2g * 1024 + s2),
            (__attribute__((address_space(3))) void*)(&alds[buf][g2 * 16]), 16, 0, 0);
        __builtin_amdgcn_global_load_lds((const __attribute__((address_space(1))) void*)(B + (size_t)r1 * 1024 + s1),
            (__attribute__((address_space(3))) void*)(&blds[buf][g1 * 16]), 16, 0, 0);
        __builtin_amdgcn_global_load_lds((const __attribute__((address_space(1))) void*)(B + (size_t)r2g * 1024 + s2),
            (__attribute__((address_space(3))) void*)(&blds[buf][g2 * 16]), 16, 0, 0);
    };

    STAGE(0, 0);
    for (int ks = 0; ks < 16; ++ks) {
        const int cur = ks & 1;
        if (ks < 15) {
            STAGE(cur ^ 1, (ks + 1) * 32);
            asm volatile("s_waitcnt vmcnt(4)" ::: "memory");
        } else {
            asm volatile("s_waitcnt vmcnt(0)" ::: "memory");
        }
        __builtin_amdgcn_s_barrier();
        asm volatile("" ::: "memory");
        s16x8 af[4], bf[4];
        #pragma unroll
        for (int mi = 0; mi < 4; ++mi) {
            int row = wr * 64 + mi * 16 + lr;
            af[mi] = *(const s16x8*)(&alds[cur][row * 64 + ((lg ^ (lr & 3)) << 4)]);
        }
        #pragma unroll
        for (int ni = 0; ni < 4; ++ni) {
            int row = wc * 64 + ni * 16 + lr;
            bf[ni] = *(const s16x8*)(&blds[cur][row * 64 + ((lg ^ (lr & 3)) << 4)]);
        }
        #pragma unroll
        for (int mi = 0; mi < 4; ++mi)
            #pragma unroll
            for (int ni = 0; ni < 4; ++ni)
                acc[mi][ni] = __builtin_amdgcn_mfma_f32_16x16x32_bf16(af[mi], bf[ni], acc[mi][ni], 0, 0, 0);
        asm volatile("" ::: "memory");
        __builtin_amdgcn_s_barrier();
    }

    #pragma unroll
    for (int ni = 0; ni < 4; ++ni) {
        int cg = c0 + wc * 64 + ni * 16 + lr;
        float bb = bp[cg];
        #pragma unroll
        for (int mi = 0; mi < 4; ++mi) {
            int row = m0 + wr * 64 + mi * 16 + lg * 4;
            #pragma unroll
            for (int r2 = 0; r2 < 4; ++r2) {
                size_t idx = (size_t)(row + r2) * 512 + cg;
                out[idx] = acc[mi][ni][r2] + bb + x[idx];
            }
        }
    }
}

extern "C" void kernel_launch(void* const* d_in, const int* in_sizes, int n_in,
                              void* d_out, int out_size, void* d_ws, size_t ws_size,
                              hipStream_t stream) {
    (void)in_sizes; (void)n_in; (void)out_size; (void)ws_size;
    const float* x     = (const float*)d_in[0];
    const float* gamma = (const float*)d_in[1];
    const float* beta  = (const float*)d_in[2];
    const float* wq    = (const float*)d_in[3];
    const float* bq    = (const float*)d_in[4];
    const float* wk    = (const float*)d_in[5];
    const float* bk    = (const float*)d_in[6];
    const float* wv    = (const float*)d_in[7];
    const float* bv    = (const float*)d_in[8];
    const float* wp    = (const float*)d_in[9];
    const float* bp    = (const float*)d_in[10];
    float* out = (float*)d_out;

    char* ws = (char*)d_ws;
    ushort_t* wt    = (ushort_t*)(ws);                 // 2 MB
    float*    stats = (float*)(ws + (2ull<<20));       // 1 KB
    ushort_t* xn    = (ushort_t*)(ws + (4ull<<20));    // 16 MB
    ushort_t* qb    = (ushort_t*)(ws + (20ull<<20));   // 16 MB
    ushort_t* kb    = (ushort_t*)(ws + (36ull<<20));   // 16 MB
    ushort_t* vt    = (ushort_t*)(ws + (52ull<<20));   // 16 MB
    ushort_t* Ob    = (ushort_t*)(ws + (68ull<<20));   // 16 MB

    hipLaunchKernelGGL(wconv_kernel,    dim3(4096),       dim3(256), 0, stream, wq, wk, wv, wp, wt);
    hipLaunchKernelGGL(gn_stats_kernel, dim3(128),        dim3(256), 0, stream, x, stats);
    hipLaunchKernelGGL(gn_norm_kernel,  dim3(8192),       dim3(256), 0, stream, x, gamma, beta, stats, xn);
    hipLaunchKernelGGL(qkv_kernel,      dim3(128, 12),    dim3(256), 0, stream, xn, wt, bq, bk, bv, qb, kb, vt);
    hipLaunchKernelGGL(attn_kernel,     dim3(64, 4),      dim3(256), 0, stream, qb, kb, vt, Ob);
    hipLaunchKernelGGL(proj_kernel,     dim3(128, 4),     dim3(256), 0, stream, Ob, wt, bp, x, out);
}